// Round 3
// baseline (196.449 us; speedup 1.0000x reference)
//
#include <hip/hip_runtime.h>

// out[t][e] = (W[e][ids[t]] + b[e]) * sqrt(512)
// W: (512, 50257) row-major f32; ids: 32768 int32; out: 32768 x 512 f32.
//
// Round 7: attack the LDS-DMA instruction count (invariant 402k width-4
// global_load_lds across R4/R5/R6, all ~63 us => instruction-path-bound).
//  - Width-16 DMA: each wave stages its 32 rows x 64 dwords with 8 dwordx4
//    instructions (1 KB each) + 2 width-4 tail instructions = 10 vs 32.
//  - Alignment: W rows are only 4B-aligned, so each row stages its 16B-
//    aligned-down 64-dword window (rowdw & ~3). Columns that fall off the
//    window top (vl >= 64-m, m = (el+vstart)&3 <= 3) come from a tail tile
//    holding real columns [60,64) of every row (width-4, dword-aligned).
//  - Bank conflicts: global source is quad-XOR-pre-swizzled (m173 pattern,
//    LDS dest stays linear): LDS quad p holds window quad p^(row&15), so a
//    column read spreads over 8 banks (~4-way, acceptable).
//  - Token list lives in REGISTERS (tok_a/tok_b) + readlane: no dependent
//    toks LDS read per iteration. Scatter unrolled 4x (8 tokens/iter).
//  - Barrier-free: waves fully independent; latency hidden by TLP
//    (grid = 3144 blocks, 4 blocks/CU by LDS).

constexpr int VOCAB = 50257;
constexpr int EMB   = 512;
constexpr int NTOK  = 8 * 4096;
constexpr float SCALE = 22.62741699796952f;  // sqrt(512)

constexpr int VB   = 64;                      // vocab ids per bucket
constexpr int NB   = (VOCAB + VB - 1) / VB;   // 786 buckets
constexpr int CAP  = 96;                      // capacity (mean 41.7, sigma 6.5)
constexpr int ESPL = 4;                       // E-slices per bucket
constexpr int RWV  = 32;                      // E-rows per wave
constexpr int MAIN_DW = RWV * 64;             // 2048 dwords main tile / wave
constexpr int TAIL_DW = RWV * 4;              // 128 dwords tail tile / wave

// d_ws int layout: counts[NB] | ocount[1] | olist[NTOK] | buckets[NB*CAP]

__global__ __launch_bounds__(256) void build_buckets(
    const int* __restrict__ ids,
    int* __restrict__ counts,
    int* __restrict__ olist,
    int* __restrict__ buckets)
{
    int t = blockIdx.x * 256 + threadIdx.x;
    int id = ids[t];
    int bkt = id >> 6;
    int slot = atomicAdd(&counts[bkt], 1);
    if (slot < CAP) {
        buckets[bkt * CAP + slot] = (t << 6) | (id & 63);
    } else {
        int o = atomicAdd(&counts[NB], 1);
        olist[o] = t;
    }
}

__global__ __launch_bounds__(256) void scatter_main(
    const float* __restrict__ W,
    const float* __restrict__ bias,
    const int*   __restrict__ counts,
    const int*   __restrict__ buckets,
    const int*   __restrict__ olist,
    const int*   __restrict__ ids,
    float*       __restrict__ out)
{
    __shared__ float tile[4][MAIN_DW + TAIL_DW];   // 34,816 B/block

    const int bid  = blockIdx.x;
    const int b    = bid >> 2;            // bucket
    const int z    = bid & 3;             // E-slice
    const int tid  = threadIdx.x;
    const int lane = tid & 63;
    const int w    = tid >> 6;            // wave id 0..3

    const int e0     = z * 128 + w * RWV; // wave's first E-row (mult of 32)
    const int vstart = min(b * VB, VOCAB - VB);
    const int vadj   = b * VB - vstart;   // 0 except last bucket (47)

    // ---- early scalar-ish loads (retire before DMA in vmcnt order) ----
    int   cnt_v = counts[b];
    int   tok_a = buckets[b * CAP + lane];                // slots 0..63
    int   tok_b = buckets[b * CAP + 64 + (lane & 31)];    // slots 64..95
    float be    = bias[e0 + (lane & 31)];

    // ---- DMA stage: 8 x width-16 (main) + 2 x width-4 (tail) ----
    {
        const int rl = lane >> 4;          // row within 4-row group
        const int p  = lane & 15;          // LDS quad position
        #pragma unroll
        for (int i = 0; i < 8; ++i) {
            const int r = 4 * i + rl;                       // wave-local row
            const int q = p ^ (r & 15);                     // window quad
            const size_t rowdw = (size_t)(e0 + r) * VOCAB + vstart;
            const float* gp = W + ((rowdw & ~(size_t)3) + 4 * (size_t)q);
            float* lp = &tile[w][i * 256];                  // wave-uniform
            __builtin_amdgcn_global_load_lds(
                (const __attribute__((address_space(1))) void*)gp,
                (__attribute__((address_space(3))) void*)lp, 16, 0, 0);
        }
        #pragma unroll
        for (int j = 0; j < 2; ++j) {
            const int f = 64 * j + lane;                    // flat tail index
            const int r = f >> 2, d = f & 3;
            const size_t rowdw = (size_t)(e0 + r) * VOCAB + vstart;
            const float* gp = W + (rowdw + 60 + d);         // real cols 60..63
            float* lp = &tile[w][MAIN_DW + j * 64];
            __builtin_amdgcn_global_load_lds(
                (const __attribute__((address_space(1))) void*)gp,
                (__attribute__((address_space(3))) void*)lp, 4, 0, 0);
        }
    }

    const int cnt = min(__builtin_amdgcn_readfirstlane(cnt_v), CAP);

    const int half = lane >> 5;
    const int el   = lane & 31;
    const int m    = (el + vstart) & 3;    // row window misalignment (dwords)
    const float* tw = &tile[w][0];

    // Wait for this wave's own DMA; other waves keep running (no barrier).
    asm volatile("s_waitcnt vmcnt(0)" ::: "memory");
    __builtin_amdgcn_sched_barrier(0);

    float* outp = out + e0 + el;

    for (int i = 0; i < cnt; i += 8) {
        float v[4]; int tt[4]; bool ok[4];
        #pragma unroll
        for (int u = 0; u < 4; ++u) {
            const int j0 = i + 2 * u;
            const int j1 = j0 + 1;
            const int jc0 = j0 < cnt ? j0 : cnt - 1;
            const int jc1 = j1 < cnt ? j1 : cnt - 1;
            const int pk0 = (jc0 < 64) ? __builtin_amdgcn_readlane(tok_a, jc0)
                                       : __builtin_amdgcn_readlane(tok_b, jc0 & 31);
            const int pk1 = (jc1 < 64) ? __builtin_amdgcn_readlane(tok_a, jc1)
                                       : __builtin_amdgcn_readlane(tok_b, jc1 & 31);
            const int pk = half ? pk1 : pk0;
            const int vl = (pk & 63) + vadj;
            const int wc = vl + m;                          // window coord
            const int a_main = el * 64 + ((((wc >> 2) ^ (el & 15))) << 2) + (wc & 3);
            const int a_tail = MAIN_DW + el * 4 + (vl - 60);
            v[u]  = tw[wc < 64 ? a_main : a_tail];          // one ds_read
            tt[u] = pk >> 6;
            ok[u] = (j0 + half) < cnt;
        }
        #pragma unroll
        for (int u = 0; u < 4; ++u)
            if (ok[u]) outp[(size_t)tt[u] * EMB] = (v[u] + be) * SCALE;
    }

    // ---- overflow fix (expected n == 0), handled by b==0 blocks ----
    if (b == 0) {
        int n = counts[NB];
        for (int ww = w; ww < n; ww += 4) {
            int t  = olist[ww];
            int id = ids[t];
            #pragma unroll
            for (int mm = 0; mm < 2; ++mm) {
                int e = z * 128 + lane + mm * 64;
                out[(size_t)t * EMB + e] = (W[(size_t)e * VOCAB + id] + bias[e]) * SCALE;
            }
        }
    }
}

// Fallback (round-1 kernel) if d_ws is too small.
__global__ __launch_bounds__(256) void embed_gather(
    const int*   __restrict__ ids,
    const float* __restrict__ W,
    const float* __restrict__ b,
    float*       __restrict__ out)
{
    int idx4 = blockIdx.x * blockDim.x + threadIdx.x;
    int t    = idx4 >> 7;
    int e    = (idx4 & 127) << 2;
    int id = ids[t];
    float4 bb = *reinterpret_cast<const float4*>(b + e);
    const float* wcol = W + (size_t)id;
    float4 o;
    o.x = (wcol[(size_t)(e + 0) * VOCAB] + bb.x) * SCALE;
    o.y = (wcol[(size_t)(e + 1) * VOCAB] + bb.y) * SCALE;
    o.z = (wcol[(size_t)(e + 2) * VOCAB] + bb.z) * SCALE;
    o.w = (wcol[(size_t)(e + 3) * VOCAB] + bb.w) * SCALE;
    *reinterpret_cast<float4*>(out + (size_t)idx4 * 4) = o;
}

extern "C" void kernel_launch(void* const* d_in, const int* in_sizes, int n_in,
                              void* d_out, int out_size, void* d_ws, size_t ws_size,
                              hipStream_t stream)
{
    const int*   ids  = (const int*)  d_in[0];
    const float* W    = (const float*)d_in[1];
    const float* bias = (const float*)d_in[2];
    float*       out  = (float*)d_out;

    const size_t ws_ints_needed = (size_t)NB + 1 + NTOK + (size_t)NB * CAP;

    if (ws_size >= ws_ints_needed * sizeof(int)) {
        int* counts  = (int*)d_ws;
        int* olist   = counts + NB + 1;
        int* buckets = olist + NTOK;

        hipMemsetAsync(counts, 0, (NB + 1) * sizeof(int), stream);
        build_buckets<<<NTOK / 256, 256, 0, stream>>>(ids, counts, olist, buckets);
        scatter_main<<<NB * ESPL, 256, 0, stream>>>(W, bias, counts, buckets,
                                                    olist, ids, out);
    } else {
        constexpr int total4 = NTOK * EMB / 4;
        embed_gather<<<total4 / 256, 256, 0, stream>>>(ids, W, bias, out);
    }
}

// Round 4
// 195.102 us; speedup vs baseline: 1.0069x; 1.0069x over previous
//
#include <hip/hip_runtime.h>

// out[t][e] = (W[e][ids[t]] + b[e]) * sqrt(512)
// W: (512, 50257) row-major f32; ids: 32768 int32; out: 32768 x 512 f32.
//
// Round 8: BISECTION — remove global_load_lds entirely (the one mechanism
// shared by all four ~63us variants). Classic reg-staging:
//   global_load_dwordx4 -> VGPR -> rotated ds_write_b128 -> ds_read scatter.
//  - Same bucket structure (VB=64, CAP=96, ESPL=4), same per-wave 32-row tile,
//    same 16B-aligned-window + 4-col tail trick for W's 4B-only row alignment.
//  - LDS swizzle now applied at WRITE time (reg-staging frees the layout):
//    row r's window quad p lands at position (p+r)&15. Column read spreads
//    ~2-4-way over banks; ds_writes are 8-way conflicted but only 10/wave.
//  - toks in LDS (R6 style) — R7's runtime-index readlane risked waterfall
//    codegen (VALUBusy 11%->20% with no perf change).
//  - One __syncthreads (toks visibility), placed after all global loads are
//    issued so load latency hides under it. No inline asm, no DMA.

constexpr int VOCAB = 50257;
constexpr int EMB   = 512;
constexpr int NTOK  = 8 * 4096;
constexpr float SCALE = 22.62741699796952f;  // sqrt(512)

constexpr int VB   = 64;                      // vocab ids per bucket
constexpr int NB   = (VOCAB + VB - 1) / VB;   // 786 buckets
constexpr int CAP  = 96;                      // capacity (mean 41.7, sigma 6.5)
constexpr int ESPL = 4;                       // E-slices per bucket
constexpr int RWV  = 32;                      // E-rows per wave
constexpr int MAIN_DW = RWV * 64;             // 2048 dwords main tile / wave
constexpr int TAIL_DW = RWV * 4;              // 128 dwords tail tile / wave

// d_ws int layout: counts[NB] | ocount[1] | olist[NTOK] | buckets[NB*CAP]

__global__ __launch_bounds__(256) void build_buckets(
    const int* __restrict__ ids,
    int* __restrict__ counts,
    int* __restrict__ olist,
    int* __restrict__ buckets)
{
    int t = blockIdx.x * 256 + threadIdx.x;
    int id = ids[t];
    int bkt = id >> 6;
    int slot = atomicAdd(&counts[bkt], 1);
    if (slot < CAP) {
        buckets[bkt * CAP + slot] = (t << 6) | (id & 63);
    } else {
        int o = atomicAdd(&counts[NB], 1);
        olist[o] = t;
    }
}

__global__ __launch_bounds__(256) void scatter_main(
    const float* __restrict__ W,
    const float* __restrict__ bias,
    const int*   __restrict__ counts,
    const int*   __restrict__ buckets,
    const int*   __restrict__ olist,
    const int*   __restrict__ ids,
    float*       __restrict__ out)
{
    __shared__ float tile[4][MAIN_DW + TAIL_DW];   // 34,816 B/block
    __shared__ int   toks[CAP];
    __shared__ int   s_cnt;

    const int bid  = blockIdx.x;
    const int b    = bid >> 2;            // bucket
    const int z    = bid & 3;             // E-slice
    const int tid  = threadIdx.x;
    const int lane = tid & 63;
    const int w    = tid >> 6;            // wave id 0..3

    const int e0     = z * 128 + w * RWV; // wave's first E-row (mult of 32)
    const int vstart = min(b * VB, VOCAB - VB);
    const int vadj   = b * VB - vstart;   // 0 except last bucket (47)

    if (tid == 0) s_cnt = counts[b];
    if (tid < CAP) toks[tid] = buckets[b * CAP + tid];

    // ---- reg-staged global loads: 8 x dwordx4 + 2-dword tail per wave ----
    const int rl = lane >> 4;             // row within 4-row group (0..3)
    const int p  = lane & 15;             // window quad index
    float4 m4[8];
    #pragma unroll
    for (int i = 0; i < 8; ++i) {
        const int r = 4 * i + rl;                           // wave-local row
        const size_t rowdw = (size_t)(e0 + r) * VOCAB + vstart;
        m4[i] = *reinterpret_cast<const float4*>(
                    W + ((rowdw & ~(size_t)3) + 4 * (size_t)p));
    }
    float tl0, tl1;
    {
        const int f0 = lane,      r0 = f0 >> 2, d0 = f0 & 3;
        const int f1 = 64 + lane, r1 = f1 >> 2, d1 = f1 & 3;
        tl0 = W[(size_t)(e0 + r0) * VOCAB + vstart + 60 + d0];
        tl1 = W[(size_t)(e0 + r1) * VOCAB + vstart + 60 + d1];
    }
    const float be = bias[e0 + (lane & 31)];

    // ---- ds_write with quad rotation (p+row)&15; wave-private tile ----
    #pragma unroll
    for (int i = 0; i < 8; ++i) {
        const int r = 4 * i + rl;
        *reinterpret_cast<float4*>(
            &tile[w][r * 64 + (((p + r) & 15) << 2)]) = m4[i];
    }
    tile[w][MAIN_DW + lane]      = tl0;
    tile[w][MAIN_DW + 64 + lane] = tl1;

    __syncthreads();                      // toks visible; tile already private
    const int cnt = min(s_cnt, CAP);

    // ---- scatter: half-wave per token, 128 B contiguous stores ----
    const int half = lane >> 5;
    const int el   = lane & 31;
    const int m    = (el + vstart) & 3;   // row window misalignment (dwords)
    const float* tw = &tile[w][0];
    float* outp = out + e0 + el;

    for (int i = 0; i < cnt; i += 2) {
        const int j  = i + half;
        const int jj = j < cnt ? j : cnt - 1;
        const int pk = toks[jj];
        const int t  = pk >> 6;
        const int vl = (pk & 63) + vadj;
        const int wc = vl + m;            // window coordinate
        const int a_main = el * 64 + ((((wc >> 2) + el) & 15) << 2) + (wc & 3);
        const int a_tail = MAIN_DW + el * 4 + (vl - 60);
        const float v = tw[wc < 64 ? a_main : a_tail];
        if (j < cnt) outp[(size_t)t * EMB] = (v + be) * SCALE;
    }

    // ---- overflow fix (expected n == 0), handled by b==0 blocks ----
    if (b == 0) {
        int n = counts[NB];
        for (int ww = w; ww < n; ww += 4) {
            int t  = olist[ww];
            int id = ids[t];
            #pragma unroll
            for (int mm = 0; mm < 2; ++mm) {
                int e = z * 128 + lane + mm * 64;
                out[(size_t)t * EMB + e] = (W[(size_t)e * VOCAB + id] + bias[e]) * SCALE;
            }
        }
    }
}

// Fallback (round-1 kernel) if d_ws is too small.
__global__ __launch_bounds__(256) void embed_gather(
    const int*   __restrict__ ids,
    const float* __restrict__ W,
    const float* __restrict__ b,
    float*       __restrict__ out)
{
    int idx4 = blockIdx.x * blockDim.x + threadIdx.x;
    int t    = idx4 >> 7;
    int e    = (idx4 & 127) << 2;
    int id = ids[t];
    float4 bb = *reinterpret_cast<const float4*>(b + e);
    const float* wcol = W + (size_t)id;
    float4 o;
    o.x = (wcol[(size_t)(e + 0) * VOCAB] + bb.x) * SCALE;
    o.y = (wcol[(size_t)(e + 1) * VOCAB] + bb.y) * SCALE;
    o.z = (wcol[(size_t)(e + 2) * VOCAB] + bb.z) * SCALE;
    o.w = (wcol[(size_t)(e + 3) * VOCAB] + bb.w) * SCALE;
    *reinterpret_cast<float4*>(out + (size_t)idx4 * 4) = o;
}

extern "C" void kernel_launch(void* const* d_in, const int* in_sizes, int n_in,
                              void* d_out, int out_size, void* d_ws, size_t ws_size,
                              hipStream_t stream)
{
    const int*   ids  = (const int*)  d_in[0];
    const float* W    = (const float*)d_in[1];
    const float* bias = (const float*)d_in[2];
    float*       out  = (float*)d_out;

    const size_t ws_ints_needed = (size_t)NB + 1 + NTOK + (size_t)NB * CAP;

    if (ws_size >= ws_ints_needed * sizeof(int)) {
        int* counts  = (int*)d_ws;
        int* olist   = counts + NB + 1;
        int* buckets = olist + NTOK;

        hipMemsetAsync(counts, 0, (NB + 1) * sizeof(int), stream);
        build_buckets<<<NTOK / 256, 256, 0, stream>>>(ids, counts, olist, buckets);
        scatter_main<<<NB * ESPL, 256, 0, stream>>>(W, bias, counts, buckets,
                                                    olist, ids, out);
    } else {
        constexpr int total4 = NTOK * EMB / 4;
        embed_gather<<<total4 / 256, 256, 0, stream>>>(ids, W, bias, out);
    }
}

// Round 5
// 188.922 us; speedup vs baseline: 1.0398x; 1.0327x over previous
//
#include <hip/hip_runtime.h>

// out[t][e] = (W[e][ids[t]] + b[e]) * sqrt(512)
// W: (512, 50257) row-major f32; ids: 32768 int32; out: 32768 x 512 f32.
//
// Round 9: recover the 1KB-contiguous-store regime (R4, the best measured
// scatter) with all later wins kept.
//  - VB=32 buckets (NB=1571). Block covers ALL 512 e-rows in 2 chunks of 256
//    (single 32KB tile, 3 barriers). 4 blocks/CU -> 16 waves/CU.
//  - Scatter: one wave per token per chunk; lane holds e = c*256 + 4*lane+k,
//    k=0..3 -> ONE dwordx4 store instruction = 1KB contiguous; both chunks of
//    a token's row come from the same block (2KB total).
//  - LDS: tile[r][32] linear (DMA-dest contiguous, m104); bank spread via
//    pre-swizzled GLOBAL source (m173): row r slot p holds col p ^ ((r>>3)&31).
//    Read slot = vl ^ ((lane>>1)&31): 2-way conflict only (free, m136).
//    DMA: 2 rows per width-4 instruction (instruction count proven irrelevant
//    R6->R7).
//  - memset for counts, overflow folded into b==0 blocks.

constexpr int VOCAB = 50257;
constexpr int EMB   = 512;
constexpr int NTOK  = 8 * 4096;
constexpr float SCALE = 22.62741699796952f;  // sqrt(512)

constexpr int VB   = 32;                      // vocab ids per bucket
constexpr int NB   = (VOCAB + VB - 1) / VB;   // 1571 buckets
constexpr int CAP  = 96;                      // capacity (mean 20.9, sigma 4.6)
constexpr int ECH  = 256;                     // e-rows per chunk
constexpr int NCH  = EMB / ECH;               // 2 chunks

// d_ws int layout: counts[NB] | ocount[1] | olist[NTOK] | buckets[NB*CAP]

__global__ __launch_bounds__(256) void build_buckets(
    const int* __restrict__ ids,
    int* __restrict__ counts,
    int* __restrict__ olist,
    int* __restrict__ buckets)
{
    int t = blockIdx.x * 256 + threadIdx.x;
    int id = ids[t];
    int bkt = id >> 5;
    int slot = atomicAdd(&counts[bkt], 1);
    if (slot < CAP) {
        buckets[bkt * CAP + slot] = (t << 5) | (id & 31);
    } else {
        int o = atomicAdd(&counts[NB], 1);
        olist[o] = t;
    }
}

__global__ __launch_bounds__(256) void scatter_main(
    const float* __restrict__ W,
    const float* __restrict__ bias,
    const int*   __restrict__ counts,
    const int*   __restrict__ buckets,
    const int*   __restrict__ olist,
    const int*   __restrict__ ids,
    float*       __restrict__ out)
{
    __shared__ float tile[ECH * VB];      // 32,768 B
    __shared__ int   toks[CAP];
    __shared__ int   s_cnt;

    const int b    = blockIdx.x;
    const int tid  = threadIdx.x;
    const int lane = tid & 63;
    const int w    = tid >> 6;            // wave id 0..3

    const int vstart = min(b * VB, VOCAB - VB);
    const int vadj   = b * VB - vstart;   // 0 except last bucket (15)

    if (tid == 0) s_cnt = counts[b];
    if (tid < CAP) toks[tid] = buckets[b * CAP + tid];

    const int pos  = lane & 31;           // LDS slot within row
    const int rh   = lane >> 5;           // row-half selector for staging
    const int cc_s = (lane >> 1) & 31;    // read-side swizzle constant

    // Per-chunk bias fragment: covers e = c*ECH + 4*lane + k.
    float4 bb[NCH];
    #pragma unroll
    for (int c = 0; c < NCH; ++c)
        bb[c] = *reinterpret_cast<const float4*>(bias + c * ECH + 4 * lane);

    int cnt = 0;

    #pragma unroll
    for (int c = 0; c < NCH; ++c) {
        // ---- stage chunk c: wave w rows [w*64, w*64+64), 2 rows/instr ----
        #pragma unroll
        for (int i = 0; i < 32; ++i) {
            const int r = w * 64 + 2 * i + rh;          // chunk-local row
            const int s = (r >> 3) & 31;                // source pre-swizzle
            const float* gp = W + ((size_t)(c * ECH + r) * VOCAB
                                   + (vstart + (pos ^ s)));
            float* lp = &tile[(w * 64 + 2 * i) * VB];   // wave-uniform base
            __builtin_amdgcn_global_load_lds(
                (const __attribute__((address_space(1))) void*)gp,
                (__attribute__((address_space(3))) void*)lp, 4, 0, 0);
        }
        __syncthreads();                  // stage visible (+ toks on c==0)
        if (c == 0) cnt = min(s_cnt, CAP);

        // ---- scatter: 1 token/wave/iter, ONE 1KB-contiguous store ----
        const float* tl = &tile[lane * 128];  // rows 4*lane..4*lane+3
        const float4 bc = bb[c];
        for (int i = w; i < cnt; i += 4) {
            const int pk = toks[i];
            const int t  = pk >> 5;
            const int vl = (pk & 31) + vadj;
            const int cc = vl ^ cc_s;     // 2-way banked (free)
            float4 o;
            o.x = tl[      cc];
            o.y = tl[ 32 + cc];
            o.z = tl[ 64 + cc];
            o.w = tl[ 96 + cc];
            o.x = (o.x + bc.x) * SCALE;
            o.y = (o.y + bc.y) * SCALE;
            o.z = (o.z + bc.z) * SCALE;
            o.w = (o.w + bc.w) * SCALE;
            *reinterpret_cast<float4*>(out + (size_t)t * EMB + c * ECH + 4 * lane) = o;
        }
        if (c + 1 < NCH) __syncthreads(); // protect tile reuse
    }

    // ---- overflow fix (expected n == 0), handled by b==0 blocks ----
    if (b == 0) {
        int n = counts[NB];
        for (int ww = w; ww < n; ww += 4) {
            int t  = olist[ww];
            int id = ids[t];
            #pragma unroll
            for (int m = 0; m < 8; ++m) {
                int e = lane + m * 64;
                out[(size_t)t * EMB + e] = (W[(size_t)e * VOCAB + id] + bias[e]) * SCALE;
            }
        }
    }
}

// Fallback (round-1 kernel) if d_ws is too small.
__global__ __launch_bounds__(256) void embed_gather(
    const int*   __restrict__ ids,
    const float* __restrict__ W,
    const float* __restrict__ b,
    float*       __restrict__ out)
{
    int idx4 = blockIdx.x * blockDim.x + threadIdx.x;
    int t    = idx4 >> 7;
    int e    = (idx4 & 127) << 2;
    int id = ids[t];
    float4 bb = *reinterpret_cast<const float4*>(b + e);
    const float* wcol = W + (size_t)id;
    float4 o;
    o.x = (wcol[(size_t)(e + 0) * VOCAB] + bb.x) * SCALE;
    o.y = (wcol[(size_t)(e + 1) * VOCAB] + bb.y) * SCALE;
    o.z = (wcol[(size_t)(e + 2) * VOCAB] + bb.z) * SCALE;
    o.w = (wcol[(size_t)(e + 3) * VOCAB] + bb.w) * SCALE;
    *reinterpret_cast<float4*>(out + (size_t)idx4 * 4) = o;
}

extern "C" void kernel_launch(void* const* d_in, const int* in_sizes, int n_in,
                              void* d_out, int out_size, void* d_ws, size_t ws_size,
                              hipStream_t stream)
{
    const int*   ids  = (const int*)  d_in[0];
    const float* W    = (const float*)d_in[1];
    const float* bias = (const float*)d_in[2];
    float*       out  = (float*)d_out;

    const size_t ws_ints_needed = (size_t)NB + 1 + NTOK + (size_t)NB * CAP;

    if (ws_size >= ws_ints_needed * sizeof(int)) {
        int* counts  = (int*)d_ws;
        int* olist   = counts + NB + 1;
        int* buckets = olist + NTOK;

        hipMemsetAsync(counts, 0, (NB + 1) * sizeof(int), stream);
        build_buckets<<<NTOK / 256, 256, 0, stream>>>(ids, counts, olist, buckets);
        scatter_main<<<NB, 256, 0, stream>>>(W, bias, counts, buckets,
                                             olist, ids, out);
    } else {
        constexpr int total4 = NTOK * EMB / 4;
        embed_gather<<<total4 / 256, 256, 0, stream>>>(ids, W, bias, out);
    }
}